// Round 9
// baseline (534.705 us; speedup 1.0000x reference)
//
#include <hip/hip_runtime.h>
#include <hip/hip_bf16.h>
#include <stdint.h>

#define T_STEPS 86
#define HDIM    64
#define VOCABSZ 257

typedef __attribute__((ext_vector_type(8))) short short8;
typedef __attribute__((ext_vector_type(4))) float f32x4;

__device__ __forceinline__ ushort f2bf(float x){
    union { float f; uint32_t u; } v; v.f = x;
    uint32_t r = v.u + 0x7fffu + ((v.u >> 16) & 1u);
    return (ushort)(r >> 16);
}
__device__ __forceinline__ float bf2f(ushort h){
    union { uint32_t u; float f; } v; v.u = ((uint32_t)h) << 16;
    return v.f;
}
__device__ __forceinline__ float sig_(float x){
    return __fdividef(1.f, 1.f + __expf(-x));
}
__device__ __forceinline__ float tanh_(float x){
    float e = __expf(2.f * x);
    return 1.f - __fdividef(2.f, e + 1.f);
}

// perm: tile tau (0..3), tile-row r (0..15) -> h-dim (0..63)
__device__ __forceinline__ int dimof(int tau, int r){
    return (tau >> 1) * 32 + (r >> 2) * 8 + (tau & 1) * 4 + (r & 3);
}

// ===== Prep 1: xg_p[tok][j*16+r] = dot(wte[tok], W_ih[gcol]) + biases, where
// gcol = G*64 + dimof(tau, r), j = G*4+tau. Exact fp32, permuted slot order so
// the recurrence lane reads its 4 D-slots as one float4.
__global__ __launch_bounds__(256) void prep_xg(
    const float* __restrict__ wte,
    const float* __restrict__ W_ih,
    const float* __restrict__ b_ih,
    const float* __restrict__ b_hh,
    float*       __restrict__ xg_p)     // [257][256]
{
    const int tok = blockIdx.x;         // 0..256
    const int s   = threadIdx.x;        // 0..255
    const int j = s >> 4, r = s & 15;
    const int G = j >> 2, tau = j & 3;
    const int gcol = G * 64 + dimof(tau, r);
    float acc = b_ih[gcol] + b_hh[gcol];
    const float* wr = wte  + (size_t)tok * HDIM;
    const float* wc = W_ih + (size_t)gcol * HDIM;
#pragma unroll 8
    for (int k = 0; k < HDIM; ++k) acc += wr[k] * wc[k];
    xg_p[tok * 256 + s] = acc;
}

// ===== Prep 2: W_hh into A-frag image, permuted rows, hi+lo parts ============
// frag (j, kt, part): lane l holds A[row=l&15][k=kt*32+(l>>4)*8+e], where
// row -> gcol = G*64 + dimof(tau, l&15). Address: ((j*2+kt)*2+part)*512 + l*8.
__global__ __launch_bounds__(256) void prep_whh(
    const float* __restrict__ W_hh,
    ushort*      __restrict__ whh_frag)  // 32768 ushorts = 64 KB
{
    const int i = blockIdx.x * 256 + threadIdx.x;   // 0..4095
    if (i < 16 * 2 * 2 * 64) {
        const int j    = i >> 8;
        const int rem  = i & 255;
        const int kt   = rem >> 7;
        const int part = (rem >> 6) & 1;
        const int l    = rem & 63;
        const int G = j >> 2, tau = j & 3;
        const int gcol = G * 64 + dimof(tau, l & 15);
        const int k0   = kt * 32 + (l >> 4) * 8;
        short8 v;
#pragma unroll
        for (int e = 0; e < 8; ++e) {
            const float f   = W_hh[(size_t)gcol * HDIM + k0 + e];
            const ushort hi = f2bf(f);
            v[e] = part ? (short)f2bf(f - bf2f(hi)) : (short)hi;
        }
        *(short8*)(whh_frag + (size_t)i * 8) = v;
    }
}

// ===== Prep 3: lm_W into MFMA B-frag layout (unchanged) ======================
__global__ __launch_bounds__(256) void prep_lm(
    const float* __restrict__ lm_W,
    ushort*      __restrict__ lm_frag)  // [17][2][512]
{
    const int i = blockIdx.x * 256 + threadIdx.x;
    if (i < 17 * 2 * 64) {
        const int n = i >> 7, rem = i & 127, kt = rem >> 6, l = rem & 63;
        const int col = n * 16 + (l & 15);
        const int k0  = kt * 32 + (l >> 4) * 8;
        short8 h8;
#pragma unroll
        for (int e = 0; e < 8; ++e)
            h8[e] = (col < VOCABSZ) ? (short)f2bf(lm_W[col * HDIM + k0 + e]) : (short)0;
        *(short8*)(lm_frag + (size_t)i * 8) = h8;
    }
}

// ===== Kernel A: recurrence — ONE autonomous wave per 16 rows, NO barriers ===
// gates^T = W_perm @ h^T : D-output registers ARE the next step's h B-frags
// (perm makes dims land in the right (kt,e') slots). EW fully lane-local.
__global__ __launch_bounds__(64) void lstm_recur6(
    const int*    __restrict__ idx,
    const float*  __restrict__ xg_p,
    const ushort* __restrict__ whh_frag,
    uint32_t*     __restrict__ h_pack)   // [B*T][64] dwords hi|lo
{
    __shared__ __align__(16) ushort wf[32768];   // 64 KB W_hh frag image
    __shared__ int idx_lds[16][T_STEPS];

    const int tid  = threadIdx.x;   // 0..63, one wave
    const int lmod = tid & 15;      // batch row within group
    const int lhi  = tid >> 4;
    const int rbase = blockIdx.x * 16;

    // stage weights + idx once (only __syncthreads in the kernel)
    for (int i = tid; i < 16 * 2 * 2 * 64; i += 64)
        *(short8*)(wf + (size_t)i * 8) = *(const short8*)(whh_frag + (size_t)i * 8);
    for (int i = tid; i < 16 * T_STEPS; i += 64) {
        const int r = i / T_STEPS, tt = i % T_STEPS;
        idx_lds[r][tt] = idx[(rbase + r) * T_STEPS + tt];
    }
    __syncthreads();

    short8 hfh[2], hfl[2];          // h(t-1) B-frags, start at 0
#pragma unroll
    for (int kt = 0; kt < 2; ++kt)
#pragma unroll
        for (int e = 0; e < 8; ++e) { hfh[kt][e] = 0; hfl[kt][e] = 0; }
    float cst[16];
#pragma unroll
    for (int q = 0; q < 16; ++q) cst[q] = 0.f;

    for (int t = 0; t < T_STEPS; ++t) {
        // token + xg gathers (consumed after MFMA phase -> latency hidden)
        const int tok = idx_lds[lmod][t];
        const float* xb = xg_p + tok * 256 + lhi * 4;
        f32x4 xgv[16];
#pragma unroll
        for (int j = 0; j < 16; ++j)
            xgv[j] = *(const f32x4*)(xb + j * 16);

        // 16 tiles x (2 kt x 3 terms) MFMA, weights streamed from LDS
        f32x4 acc[16];
#pragma unroll
        for (int j = 0; j < 16; ++j) acc[j] = (f32x4){0.f, 0.f, 0.f, 0.f};
#pragma unroll
        for (int j = 0; j < 16; ++j) {
#pragma unroll
            for (int kt = 0; kt < 2; ++kt) {
                const short8 wh = *(const short8*)(wf + (((j * 2 + kt) * 2 + 0) * 64 + tid) * 8);
                const short8 wl = *(const short8*)(wf + (((j * 2 + kt) * 2 + 1) * 64 + tid) * 8);
                acc[j] = __builtin_amdgcn_mfma_f32_16x16x32_bf16(wh, hfh[kt], acc[j], 0, 0, 0);
                acc[j] = __builtin_amdgcn_mfma_f32_16x16x32_bf16(wh, hfl[kt], acc[j], 0, 0, 0);
                acc[j] = __builtin_amdgcn_mfma_f32_16x16x32_bf16(wl, hfh[kt], acc[j], 0, 0, 0);
            }
        }

        // elementwise LSTM: i/f/g/o lane-local; D-slots -> next B-frag slots
        uint32_t pk[16];
#pragma unroll
        for (int tau = 0; tau < 4; ++tau) {
#pragma unroll
            for (int e = 0; e < 4; ++e) {
                const float iv = acc[tau][e]      + xgv[tau][e];
                const float fv = acc[4 + tau][e]  + xgv[4 + tau][e];
                const float gv = acc[8 + tau][e]  + xgv[8 + tau][e];
                const float ov = acc[12 + tau][e] + xgv[12 + tau][e];
                const float cn = sig_(fv) * cst[tau * 4 + e] + sig_(iv) * tanh_(gv);
                cst[tau * 4 + e] = cn;
                const float hv = sig_(ov) * tanh_(cn);
                const ushort hh = f2bf(hv);
                const ushort hl = f2bf(hv - bf2f(hh));
                const int kt = tau >> 1;
                const int ep = (tau & 1) * 4 + e;
                hfh[kt][ep] = (short)hh;
                hfl[kt][ep] = (short)hl;
                pk[kt * 8 + ep] = (uint32_t)hh | ((uint32_t)hl << 16);
            }
        }

        // coalesced h store (natural dim order; fire-and-forget)
        uint32_t* hb = h_pack + ((size_t)(rbase + lmod) * T_STEPS + t) * HDIM + lhi * 8;
        uint4 s0, s1, s2, s3;
        s0.x = pk[0];  s0.y = pk[1];  s0.z = pk[2];  s0.w = pk[3];
        s1.x = pk[4];  s1.y = pk[5];  s1.z = pk[6];  s1.w = pk[7];
        s2.x = pk[8];  s2.y = pk[9];  s2.z = pk[10]; s2.w = pk[11];
        s3.x = pk[12]; s3.y = pk[13]; s3.z = pk[14]; s3.w = pk[15];
        *(uint4*)(hb)      = s0;
        *(uint4*)(hb + 4)  = s1;
        *(uint4*)(hb + 32) = s2;
        *(uint4*)(hb + 36) = s3;
        // no barrier — single wave owns everything
    }
}

// ===== Kernel B: logits GEMM, LDS-free (unchanged from R8) ===================
__global__ __launch_bounds__(256) void lstm_logits2(
    const uint32_t* __restrict__ h_pack,
    const ushort*   __restrict__ lm_frag,
    const float*    __restrict__ lm_b,
    float*          __restrict__ out)
{
    const int tid  = threadIdx.x;
    const int wave = tid >> 6;
    const int lane = tid & 63;
    const int lmod = lane & 15;
    const int lhi  = lane >> 4;
    const size_t row0 = (size_t)blockIdx.x * 64 + wave * 16;

    short8 ah[2], al[2];
#pragma unroll
    for (int kt = 0; kt < 2; ++kt) {
        const uint32_t* src = h_pack + (row0 + lmod) * HDIM + kt * 32 + lhi * 8;
        const uint4 q0 = *(const uint4*)(src);
        const uint4 q1 = *(const uint4*)(src + 4);
        const uint32_t q[8] = {q0.x, q0.y, q0.z, q0.w, q1.x, q1.y, q1.z, q1.w};
        short8 a_, b_;
#pragma unroll
        for (int e = 0; e < 8; ++e) {
            a_[e] = (short)(q[e] & 0xffffu);
            b_[e] = (short)(q[e] >> 16);
        }
        ah[kt] = a_; al[kt] = b_;
    }

#pragma unroll 4
    for (int n = 0; n < 17; ++n) {
        const short8 bh0 = *(const short8*)(lm_frag + ((n * 2 + 0) * 512 + lane * 8));
        const short8 bh1 = *(const short8*)(lm_frag + ((n * 2 + 1) * 512 + lane * 8));
        const int v = n * 16 + lmod;
        const float bias = (v < VOCABSZ) ? lm_b[v] : 0.f;
        f32x4 acc = {bias, bias, bias, bias};
        acc = __builtin_amdgcn_mfma_f32_16x16x32_bf16(ah[0], bh0, acc, 0, 0, 0);
        acc = __builtin_amdgcn_mfma_f32_16x16x32_bf16(al[0], bh0, acc, 0, 0, 0);
        acc = __builtin_amdgcn_mfma_f32_16x16x32_bf16(ah[1], bh1, acc, 0, 0, 0);
        acc = __builtin_amdgcn_mfma_f32_16x16x32_bf16(al[1], bh1, acc, 0, 0, 0);
        if (v < VOCABSZ) {
#pragma unroll
            for (int e = 0; e < 4; ++e)
                out[(row0 + lhi * 4 + e) * VOCABSZ + v] = acc[e];
        }
    }
}

// ===== Fallback: fused kernel (used only if ws too small) ====================
__global__ __launch_bounds__(512) void lstm_fused_fb(
    const int*   __restrict__ idx,
    const float* __restrict__ wte,
    const float* __restrict__ W_ih,
    const float* __restrict__ W_hh,
    const float* __restrict__ b_ih,
    const float* __restrict__ b_hh,
    const float* __restrict__ lm_W,
    const float* __restrict__ lm_b,
    float*       __restrict__ out)
{
    __shared__ __align__(16) ushort a_hi[16 * 128];
    __shared__ __align__(16) ushort a_lo[16 * 128];
    __shared__ float g_lds[8 * 260];
    __shared__ int   idx_lds[8][T_STEPS];

    const int tid  = threadIdx.x;
    const int wave = tid >> 6;
    const int lane = tid & 63;
    const int lmod = lane & 15;
    const int lhi  = lane >> 4;
    const int rbase = blockIdx.x * 8;

    short8 wbh[2][4], wbl[2][4];
    float  gbias[2];
#pragma unroll
    for (int n = 0; n < 2; ++n) {
        const int col = wave * 32 + n * 16 + lmod;
        gbias[n] = b_ih[col] + b_hh[col];
#pragma unroll
        for (int kt = 0; kt < 4; ++kt) {
            const int k0 = (kt & 1) * 32 + lhi * 8;
            const float* src = (kt < 2 ? W_ih : W_hh) + col * HDIM + k0;
            short8 h8, l8;
#pragma unroll
            for (int e = 0; e < 8; ++e) {
                float f   = src[e];
                ushort hh = f2bf(f);
                h8[e] = (short)hh;
                l8[e] = (short)f2bf(f - bf2f(hh));
            }
            wbh[n][kt] = h8; wbl[n][kt] = l8;
        }
    }
    short8 lmh[2][2];
    float  lmbias[2];
#pragma unroll
    for (int ni = 0; ni < 2; ++ni) {
        const int v = (2 * wave + ni) * 16 + lmod;
        lmbias[ni] = lm_b[v];
#pragma unroll
        for (int kt = 0; kt < 2; ++kt) {
            const int k0 = kt * 32 + lhi * 8;
            short8 h8;
#pragma unroll
            for (int e = 0; e < 8; ++e) h8[e] = (short)f2bf(lm_W[v * HDIM + k0 + e]);
            lmh[ni][kt] = h8;
        }
    }
    const float w256r = lm_W[256 * HDIM + lane];
    const float b256  = lm_b[256];

    for (int i = tid; i < 16 * 128; i += 512) { a_hi[i] = 0; a_lo[i] = 0; }
    for (int i = tid; i < 8 * T_STEPS; i += 512) {
        const int r = i / T_STEPS, tt = i % T_STEPS;
        idx_lds[r][tt] = idx[(rbase + r) * T_STEPS + tt];
    }
    __syncthreads();
    if (tid < 8 * 16) {
        const int r = tid >> 4, j4 = (tid & 15) * 4;
        const int token = idx_lds[r][0];
        const float4 vv = *(const float4*)(wte + (size_t)token * HDIM + j4);
        const float fv[4] = {vv.x, vv.y, vv.z, vv.w};
#pragma unroll
        for (int e = 0; e < 4; ++e) {
            const ushort hh = f2bf(fv[e]);
            const int ix = (r * 128 + j4 + e) ^ ((r & 7) << 3);
            a_hi[ix] = hh;
            a_lo[ix] = f2bf(fv[e] - bf2f(hh));
        }
    }
    __syncthreads();

    float cstate = 0.f;
    for (int t = 0; t < T_STEPS; ++t) {
        f32x4 acc0 = {gbias[0], gbias[0], gbias[0], gbias[0]};
        f32x4 acc1 = {gbias[1], gbias[1], gbias[1], gbias[1]};
#pragma unroll
        for (int kt = 0; kt < 4; ++kt) {
            const int ix = (lmod * 128 + kt * 32 + lhi * 8) ^ ((lmod & 7) << 3);
            const short8 ah = *(const short8*)(a_hi + ix);
            const short8 al = *(const short8*)(a_lo + ix);
            acc0 = __builtin_amdgcn_mfma_f32_16x16x32_bf16(ah, wbh[0][kt], acc0, 0, 0, 0);
            acc0 = __builtin_amdgcn_mfma_f32_16x16x32_bf16(ah, wbl[0][kt], acc0, 0, 0, 0);
            acc0 = __builtin_amdgcn_mfma_f32_16x16x32_bf16(al, wbh[0][kt], acc0, 0, 0, 0);
            acc1 = __builtin_amdgcn_mfma_f32_16x16x32_bf16(ah, wbh[1][kt], acc1, 0, 0, 0);
            acc1 = __builtin_amdgcn_mfma_f32_16x16x32_bf16(ah, wbl[1][kt], acc1, 0, 0, 0);
            acc1 = __builtin_amdgcn_mfma_f32_16x16x32_bf16(al, wbh[1][kt], acc1, 0, 0, 0);
        }
        if (lhi < 2) {
#pragma unroll
            for (int e = 0; e < 4; ++e) {
                const int row = lhi * 4 + e;
                g_lds[row * 260 + wave * 32 + lmod]      = acc0[e];
                g_lds[row * 260 + wave * 32 + 16 + lmod] = acc1[e];
            }
        }
        __syncthreads();
        float4 vv;
        const bool do_stage = (t + 1 < T_STEPS) && (tid < 8 * 16);
        const int sr = tid >> 4, sj4 = (tid & 15) * 4;
        if (do_stage) {
            const int token = idx_lds[sr][t + 1];
            vv = *(const float4*)(wte + (size_t)token * HDIM + sj4);
        }
        {
            const float* gr = g_lds + wave * 260;
            const float iv = gr[lane];
            const float fv = gr[64 + lane];
            const float gv = gr[128 + lane];
            const float ov = gr[192 + lane];
            const float cn = sig_(fv) * cstate + sig_(iv) * tanh_(gv);
            cstate = cn;
            const float hv = sig_(ov) * tanh_(cn);
            const ushort hh = f2bf(hv);
            const int ix = (wave * 128 + 64 + lane) ^ ((wave & 7) << 3);
            a_hi[ix] = hh;
            a_lo[ix] = f2bf(hv - bf2f(hh));
            float p256 = hv * w256r;
#pragma unroll
            for (int off = 32; off; off >>= 1) p256 += __shfl_xor(p256, off);
            if (lane == 0)
                out[(size_t)(rbase + wave) * (T_STEPS * VOCABSZ) + (size_t)t * VOCABSZ + 256]
                    = p256 + b256;
        }
        if (do_stage) {
            const float fv[4] = {vv.x, vv.y, vv.z, vv.w};
#pragma unroll
            for (int e = 0; e < 4; ++e) {
                const ushort hh = f2bf(fv[e]);
                const int ix = (sr * 128 + sj4 + e) ^ ((sr & 7) << 3);
                a_hi[ix] = hh;
                a_lo[ix] = f2bf(fv[e] - bf2f(hh));
            }
        }
        __syncthreads();
        short8 lah[2], lal[2];
#pragma unroll
        for (int kt = 0; kt < 2; ++kt) {
            const int ix = (lmod * 128 + 64 + kt * 32 + lhi * 8) ^ ((lmod & 7) << 3);
            lah[kt] = *(const short8*)(a_hi + ix);
            lal[kt] = *(const short8*)(a_lo + ix);
        }
#pragma unroll
        for (int ni = 0; ni < 2; ++ni) {
            f32x4 acc = {lmbias[ni], lmbias[ni], lmbias[ni], lmbias[ni]};
#pragma unroll
            for (int kt = 0; kt < 2; ++kt) {
                acc = __builtin_amdgcn_mfma_f32_16x16x32_bf16(lah[kt], lmh[ni][kt], acc, 0, 0, 0);
                acc = __builtin_amdgcn_mfma_f32_16x16x32_bf16(lal[kt], lmh[ni][kt], acc, 0, 0, 0);
            }
            const int v = (2 * wave + ni) * 16 + lmod;
            if (lhi < 2) {
#pragma unroll
                for (int e = 0; e < 4; ++e) {
                    const int r = rbase + lhi * 4 + e;
                    out[(size_t)r * (T_STEPS * VOCABSZ) + (size_t)t * VOCABSZ + v] = acc[e];
                }
            }
        }
    }
}

extern "C" void kernel_launch(void* const* d_in, const int* in_sizes, int n_in,
                              void* d_out, int out_size, void* d_ws, size_t ws_size,
                              hipStream_t stream) {
    const int*   idx  = (const int*)  d_in[0];
    const float* wte  = (const float*)d_in[1];
    const float* W_ih = (const float*)d_in[2];
    const float* W_hh = (const float*)d_in[3];
    const float* b_ih = (const float*)d_in[4];
    const float* b_hh = (const float*)d_in[5];
    const float* lm_W = (const float*)d_in[6];
    const float* lm_b = (const float*)d_in[7];
    float* out = (float*)d_out;

    const int B = in_sizes[0] / T_STEPS;                       // 4096
    const size_t hbytes  = (size_t)B * T_STEPS * HDIM * 4;     // 90.2 MB
    const size_t xbytes  = (size_t)VOCABSZ * 256 * 4;          // 263 KB
    const size_t lbytes  = (size_t)17 * 2 * 512 * 2;           // 34.8 KB
    const size_t wfbytes = (size_t)32768 * 2;                  // 64 KB
    const size_t need    = hbytes + xbytes + lbytes + wfbytes;

    if (ws_size >= need) {
        uint32_t* h_pack   = (uint32_t*)d_ws;
        float*    xg_p     = (float*)  ((char*)d_ws + hbytes);
        ushort*   lm_frag  = (ushort*) ((char*)d_ws + hbytes + xbytes);
        ushort*   whh_frag = (ushort*) ((char*)d_ws + hbytes + xbytes + lbytes);

        prep_xg<<<VOCABSZ, 256, 0, stream>>>(wte, W_ih, b_ih, b_hh, xg_p);
        prep_whh<<<16, 256, 0, stream>>>(W_hh, whh_frag);
        prep_lm<<<9, 256, 0, stream>>>(lm_W, lm_frag);
        lstm_recur6<<<B / 16, 64, 0, stream>>>(idx, xg_p, whh_frag, h_pack);
        lstm_logits2<<<(B * T_STEPS) / 64, 256, 0, stream>>>(h_pack, lm_frag, lm_b, out);
    } else {
        lstm_fused_fb<<<B / 8, 512, 0, stream>>>(idx, wte, W_ih, W_hh, b_ih, b_hh,
                                                 lm_W, lm_b, out);
    }
}